// Round 9
// baseline (131.051 us; speedup 1.0000x reference)
//
#include <hip/hip_runtime.h>

// QueryAndGroup: ball_query(r=0.2, ns=32) + group xyz (centered) + group features.
//   xyz      [8][16384][3] f32   d_in[0]
//   new_xyz  [8][1024][3]  f32   d_in[1]
//   features [8][64][16384] f32  d_in[2]
//   out      [8][67][1024][32] f32
//
// R8 evidence: packed-f4 coords raised line-requests (32 vs SoA 24 per 128 pts)
// -> revert to SoA. Three neutral rounds => the conserved term is the scan's
// straggler tail (corner queries scan 16384 pts = 128 serialized iters).
// R9: 2 waves per query, each scans half the index range; ordered merge is
// concat (half0 indices < half1) after one __syncthreads. Tail 128 -> 64 iters;
// avg work x2 but VALUBusy was only 12% -> latency-bound trade is favorable.

#define N_PTS   16384
#define M_Q     1024
#define B_SZ    8
#define NSAMP   32
#define NCH     64
#define R2      0.04f
#define OUT_CH  (3 + NCH)
#define HALF_N  (N_PTS / 2)

typedef float f4 __attribute__((ext_vector_type(4)));

// ---------- K0: xyz AoS -> SoA (1.5 MB, ~1-2us) ----------
__global__ __launch_bounds__(256) void soa_kernel(
    const float* __restrict__ xyz,
    float* __restrict__ xs, float* __restrict__ ys, float* __restrict__ zs)
{
    const int i = blockIdx.x * 256 + threadIdx.x;       // 0..131071 = B*N
    const float* src = xyz + (size_t)i * 3;
    xs[i] = src[0];
    ys[i] = src[1];
    zs[i] = src[2];
}

// ---------- K1 fat: transpose tiles || split ball query ----------
// 6144 blocks. b = blockIdx&7 (XCD affinity for both paths).
// g = blockIdx>>3 in [0,768): g%3==0 -> transpose tile (256 per b);
// else query block (512 per b), 2 queries x 2 half-scan waves.
__global__ __launch_bounds__(256) void fat_kernel(
    const float* __restrict__ feat,     // [B][C][N]
    const float* __restrict__ new_xyz,  // [B][M][3]
    const float* __restrict__ xs, const float* __restrict__ ys,
    const float* __restrict__ zs,
    float* __restrict__ ft,             // [B][N][C]
    int*   __restrict__ meta,           // [B*M][NSAMP] sample indices
    float* __restrict__ out)            // [B][67][M][NS] (xyz channels written here)
{
    __shared__ float tile[64][65];                  // transpose path (16.6 KB)
    __shared__ float lists[2][2][NSAMP][4];         // [query][half][slot]{dx,dy,dz,idx}
    __shared__ int   kcnt[2][2];
    __shared__ float fin[2][NSAMP][4];

    const int tid = threadIdx.x;
    const int b   = blockIdx.x & 7;
    const int g   = blockIdx.x >> 3;                // 0..767
    const int g3  = g / 3;
    const int r3  = g - g3 * 3;

    if (r3 == 0) {
        // ---- transpose tile: feat[b][:, n0:n0+64] -> ft[b][n0:n0+64][:] ----
        const int n0 = g3 << 6;
        const float* __restrict__ fb = feat + (size_t)b * NCH * N_PTS;
        float* __restrict__ tb       = ft   + ((size_t)b * N_PTS + n0) * NCH;
#pragma unroll
        for (int j = 0; j < 16; ++j) {              // read coalesced along n
            const int idx = j * 256 + tid;
            const int c = idx >> 6, nn = idx & 63;
            tile[c][nn] = __builtin_nontemporal_load(&fb[(size_t)c * N_PTS + n0 + nn]);
        }
        __syncthreads();
        const int c4 = tid & 15;
        const int r  = tid >> 4;
#pragma unroll
        for (int j = 0; j < 4; ++j) {               // write 1KB dwordx4 per instr
            const int nn = j * 16 + r;
            f4 o;
            o.x = tile[c4 * 4 + 0][nn];
            o.y = tile[c4 * 4 + 1][nn];
            o.z = tile[c4 * 4 + 2][nn];
            o.w = tile[c4 * 4 + 3][nn];
            *(f4*)(&tb[(size_t)nn * NCH + c4 * 4]) = o;   // re-read by K2: keep cached
        }
        return;
    }

    // ---- query path: 4 waves = 2 queries x 2 half-scans ----
    const int w    = tid >> 6;
    const int lane = tid & 63;
    const int ql   = w >> 1;                        // query-in-block 0..1
    const int h    = w & 1;                         // half 0..1
    const int v    = g3 * 2 + (r3 - 1);             // query-block id 0..511 per b
    const int m    = v * 2 + ql;
    const int q    = (b << 10) + m;

    const float cx = new_xyz[q * 3 + 0];
    const float cy = new_xyz[q * 3 + 1];
    const float cz = new_xyz[q * 3 + 2];
    const float* __restrict__ xsb = xs + (size_t)b * N_PTS;
    const float* __restrict__ ysb = ys + (size_t)b * N_PTS;
    const float* __restrict__ zsb = zs + (size_t)b * N_PTS;

    // ---- ordered half-scan: [h*8192, (h+1)*8192), 2x64/iter, prefetch next 128 ----
    const int start = h * HALF_N;
    const unsigned long long lt = (1ull << lane) - 1ull;
    int cnt = 0;
    float Ax = xsb[start + lane],      Ay = ysb[start + lane],      Az = zsb[start + lane];
    float Bx = xsb[start + 64 + lane], By = ysb[start + 64 + lane], Bz = zsb[start + 64 + lane];

    for (int base = start; ; base += 128) {
        const int  nbase = base + 128;
        const bool more  = nbase < start + HALF_N;
        const int  pA = more ? nbase + lane : start + lane;   // dummy reload (L1 hit)
        const int  pB = pA + 64;
        const float nAx = xsb[pA], nAy = ysb[pA], nAz = zsb[pA];
        const float nBx = xsb[pB], nBy = ysb[pB], nBz = zsb[pB];

        {   // chunk A (index order before B)
            const float dx = __fsub_rn(cx, Ax), dy = __fsub_rn(cy, Ay), dz = __fsub_rn(cz, Az);
            const float d2 = __fadd_rn(__fadd_rn(__fmul_rn(dx, dx), __fmul_rn(dy, dy)),
                                       __fmul_rn(dz, dz));
            const bool hit = d2 < R2;
            const unsigned long long mk = __ballot(hit);
            if (hit) {
                const int slot = cnt + __popcll(mk & lt);
                if (slot < NSAMP) {
                    lists[ql][h][slot][0] = -dx;        // = x - cx (exact negation)
                    lists[ql][h][slot][1] = -dy;
                    lists[ql][h][slot][2] = -dz;
                    lists[ql][h][slot][3] = __int_as_float(base + lane);
                }
            }
            cnt += (int)__popcll(mk);
        }
        {   // chunk B
            const float dx = __fsub_rn(cx, Bx), dy = __fsub_rn(cy, By), dz = __fsub_rn(cz, Bz);
            const float d2 = __fadd_rn(__fadd_rn(__fmul_rn(dx, dx), __fmul_rn(dy, dy)),
                                       __fmul_rn(dz, dz));
            const bool hit = d2 < R2;
            const unsigned long long mk = __ballot(hit);
            if (hit) {
                const int slot = cnt + __popcll(mk & lt);
                if (slot < NSAMP) {
                    lists[ql][h][slot][0] = -dx;
                    lists[ql][h][slot][1] = -dy;
                    lists[ql][h][slot][2] = -dz;
                    lists[ql][h][slot][3] = __int_as_float(base + 64 + lane);
                }
            }
            cnt += (int)__popcll(mk);
        }
        if (cnt >= NSAMP || !more) break;
        Ax = nAx; Ay = nAy; Az = nAz;
        Bx = nBx; By = nBy; Bz = nBz;
    }
    if (lane == 0) kcnt[ql][h] = (cnt < NSAMP) ? cnt : NSAMP;

    __syncthreads();   // both halves of both queries done

    // ---- merge (wave h==0 of each query): final = concat(list0, list1)[0:32] ----
    if (h == 0 && lane < NSAMP) {
        const int k0 = kcnt[ql][0];
        const int k1 = kcnt[ql][1];
        float e0, e1, e2, e3;
        int src_h, src_s;
        if (lane < k0)           { src_h = 0; src_s = lane; }
        else if (lane - k0 < k1) { src_h = 1; src_s = lane - k0; }
        else if (k0 > 0)         { src_h = 0; src_s = 0; }          // broadcast first
        else if (k1 > 0)         { src_h = 1; src_s = 0; }
        else                     { src_h = -1; src_s = 0; }          // no hits (never in data)
        if (src_h >= 0) {
            e0 = lists[ql][src_h][src_s][0];
            e1 = lists[ql][src_h][src_s][1];
            e2 = lists[ql][src_h][src_s][2];
            e3 = lists[ql][src_h][src_s][3];
        } else {
            e0 = __fsub_rn(xsb[0], cx); e1 = __fsub_rn(ysb[0], cy);
            e2 = __fsub_rn(zsb[0], cz); e3 = __int_as_float(0);
        }
        meta[(size_t)q * NSAMP + lane] = __float_as_int(e3);
        fin[ql][lane][0] = e0;
        fin[ql][lane][1] = e1;
        fin[ql][lane][2] = e2;
        fin[ql][lane][3] = e3;
    }

    // ---- centered-xyz channels to out (wave h==0, 24 lanes, dwordx4 nt) ----
    // wave-synchronous: fin written by this same wave above
    if (h == 0 && lane < 24) {
        const int c  = lane >> 3;        // 0..2
        const int s4 = lane & 7;
        float* __restrict__ ob = out + ((size_t)b * OUT_CH * M_Q + (size_t)m) * NSAMP;
        f4 o;
        o.x = fin[ql][s4 * 4 + 0][c];
        o.y = fin[ql][s4 * 4 + 1][c];
        o.z = fin[ql][s4 * 4 + 2][c];
        o.w = fin[ql][s4 * 4 + 3][c];
        __builtin_nontemporal_store(o, (f4*)&ob[(size_t)c * (M_Q * NSAMP) + s4 * 4]);
    }
}

// ---------- K2: dense feature gather. Transaction-minimal. ----------
__global__ __launch_bounds__(256) void group_kernel(
    const int*   __restrict__ meta,     // [B*M][NSAMP]
    const float* __restrict__ ft,       // [B][N][C]
    float* __restrict__ out)            // [B][67][M][NS]
{
    const int tid  = threadIdx.x;
    const int w    = tid >> 6;
    const int lane = tid & 63;
    const int b    = blockIdx.x & 7;                // XCD swizzle matches K1
    const int m    = ((blockIdx.x >> 3) << 2) + w;
    const int q    = (b << 10) + m;

    __shared__ int   ishare[4][NSAMP];
    __shared__ float tile[4][32][33];

    if (lane < NSAMP)
        ishare[w][lane] = meta[(size_t)q * NSAMP + lane];

    float* __restrict__ ob = out + ((size_t)b * OUT_CH * M_Q + (size_t)m) * NSAMP;
    const float* __restrict__ ftb = ft + (size_t)b * N_PTS * NCH;
    const int sgrp = lane >> 3;          // 0..7
    const int c4   = lane & 7;

#pragma unroll
    for (int chunk = 0; chunk < 2; ++chunk) {
        f4 vals[4];
#pragma unroll
        for (int i = 0; i < 4; ++i) {    // 8 lanes x 128B per row-half
            const int s = i * 8 + sgrp;
            const int n = ishare[w][s];
            vals[i] = *(const f4*)(ftb + (size_t)n * NCH + chunk * 32 + c4 * 4);
        }
#pragma unroll
        for (int i = 0; i < 4; ++i) {    // [s][c] -> [c][s]
            const int s = i * 8 + sgrp;
            tile[w][c4 * 4 + 0][s] = vals[i].x;
            tile[w][c4 * 4 + 1][s] = vals[i].y;
            tile[w][c4 * 4 + 2][s] = vals[i].z;
            tile[w][c4 * 4 + 3][s] = vals[i].w;
        }
#pragma unroll
        for (int j = 0; j < 4; ++j) {    // 1KB nt store per instr
            const int c_loc = j * 8 + (lane >> 3);
            const int s4    = lane & 7;
            f4 o;
            o.x = tile[w][c_loc][s4 * 4 + 0];
            o.y = tile[w][c_loc][s4 * 4 + 1];
            o.z = tile[w][c_loc][s4 * 4 + 2];
            o.w = tile[w][c_loc][s4 * 4 + 3];
            __builtin_nontemporal_store(
                o, (f4*)&ob[(size_t)(3 + chunk * 32 + c_loc) * (M_Q * NSAMP) + s4 * 4]);
        }
    }
}

// ---------- fallback (ws too small): direct-gather kernel ----------
__global__ __launch_bounds__(256) void qg_fallback(
    const float* __restrict__ xyz, const float* __restrict__ new_xyz,
    const float* __restrict__ feat, float* __restrict__ out)
{
    const int tid  = threadIdx.x;
    const int w    = tid >> 6;
    const int lane = tid & 63;
    const int q    = blockIdx.x * 4 + w;
    const int b    = q >> 10;
    const int m    = q & (M_Q - 1);

    __shared__ int idx_sh[4][NSAMP];

    const float cx = new_xyz[q * 3 + 0];
    const float cy = new_xyz[q * 3 + 1];
    const float cz = new_xyz[q * 3 + 2];
    const float* __restrict__ xb = xyz + (size_t)b * N_PTS * 3;

    int cnt = 0;
    for (int base = 0; base < N_PTS && cnt < NSAMP; base += 64) {
        const int n = base + lane;
        const float dx = __fsub_rn(cx, xb[n * 3 + 0]);
        const float dy = __fsub_rn(cy, xb[n * 3 + 1]);
        const float dz = __fsub_rn(cz, xb[n * 3 + 2]);
        const float d2 = __fadd_rn(__fadd_rn(__fmul_rn(dx, dx), __fmul_rn(dy, dy)),
                                   __fmul_rn(dz, dz));
        const bool hit = d2 < R2;
        const unsigned long long mk = __ballot(hit);
        if (hit) {
            const int slot = cnt + __popcll(mk & ((1ull << lane) - 1ull));
            if (slot < NSAMP) idx_sh[w][slot] = n;
        }
        cnt += (int)__popcll(mk);
    }
    __syncthreads();
    if (lane < NSAMP) {
        const int v0 = (cnt > 0) ? idx_sh[w][0] : 0;
        if (lane >= cnt) idx_sh[w][lane] = v0;
    }
    __syncthreads();

    const float* __restrict__ fb = feat + (size_t)b * NCH * N_PTS;
    float* __restrict__ ob = out + ((size_t)b * OUT_CH * M_Q + (size_t)m) * NSAMP;
    for (int e = lane; e < OUT_CH * NSAMP; e += 64) {
        const int c = e >> 5, s = e & 31;
        const int n = idx_sh[w][s];
        float v;
        if (c < 3) {
            const float ctr = (c == 0) ? cx : ((c == 1) ? cy : cz);
            v = __fsub_rn(xb[n * 3 + c], ctr);
        } else {
            v = fb[(size_t)(c - 3) * N_PTS + n];
        }
        ob[(size_t)c * (M_Q * NSAMP) + s] = v;
    }
}

extern "C" void kernel_launch(void* const* d_in, const int* in_sizes, int n_in,
                              void* d_out, int out_size, void* d_ws, size_t ws_size,
                              hipStream_t stream) {
    const float* xyz     = (const float*)d_in[0];
    const float* new_xyz = (const float*)d_in[1];
    const float* feat    = (const float*)d_in[2];
    float* out           = (float*)d_out;

    const size_t ft_elems   = (size_t)B_SZ * N_PTS * NCH;       // 8388608 floats
    const size_t soa_elems  = (size_t)B_SZ * N_PTS;             // 131072
    const size_t meta_elems = (size_t)B_SZ * M_Q * NSAMP;       // 262144 ints
    const size_t need = (ft_elems + 3 * soa_elems) * sizeof(float)
                      + meta_elems * sizeof(int);               // ~36.1 MB

    float* ft   = (float*)d_ws;
    float* xs   = ft + ft_elems;
    float* ys   = xs + soa_elems;
    float* zs   = ys + soa_elems;
    int*   meta = (int*)(zs + soa_elems);

    if (ws_size >= need) {
        soa_kernel<<<(B_SZ * N_PTS) / 256, 256, 0, stream>>>(xyz, xs, ys, zs);
        fat_kernel<<<6144, 256, 0, stream>>>(feat, new_xyz, xs, ys, zs, ft, meta, out);
        group_kernel<<<(B_SZ * M_Q) / 4, 256, 0, stream>>>(meta, ft, out);
    } else {
        qg_fallback<<<(B_SZ * M_Q) / 4, 256, 0, stream>>>(xyz, new_xyz, feat, out);
    }
}

// Round 10
// 129.571 us; speedup vs baseline: 1.0114x; 1.0114x over previous
//
#include <hip/hip_runtime.h>

// QueryAndGroup: ball_query(r=0.2, ns=32) + group xyz (centered) + group features.
//   xyz      [8][16384][3] f32   d_in[0]
//   new_xyz  [8][1024][3]  f32   d_in[1]
//   features [8][64][16384] f32  d_in[2]
//   out      [8][67][1024][32] f32
//
// R9 evidence: duration tracks total scan line-requests (R8 +33% lines -> +2us;
// R9 2x scan work -> +3us), NOT tail length => scan is TA-throughput bound.
// R10: block-shared LDS staging. 4 waves/block scanned the same stream
// independently (96 lines/128pts/block); now all 256 threads stage 256 pts/iter
// into double-buffered LDS (48 lines/block = 4x tx cut), each wave ballots
// against LDS. Exit at max-of-4 scan length (~1.5x mean) -> net ~2.6x fewer tx.
// Base = R6 structure (best measured, 125.6us): soa + transpose + fused qg_main.

#define N_PTS   16384
#define M_Q     1024
#define B_SZ    8
#define NSAMP   32
#define NCH     64
#define R2      0.04f
#define OUT_CH  (3 + NCH)
#define CHUNK   256

typedef float f4 __attribute__((ext_vector_type(4)));

// ---------- K0: xyz AoS -> SoA (1.5 MB, ~1-2us) ----------
__global__ __launch_bounds__(256) void soa_kernel(
    const float* __restrict__ xyz,
    float* __restrict__ xs, float* __restrict__ ys, float* __restrict__ zs)
{
    const int i = blockIdx.x * 256 + threadIdx.x;       // 0..131071 = B*N
    const float* src = xyz + (size_t)i * 3;
    xs[i] = src[0];
    ys[i] = src[1];
    zs[i] = src[2];
}

// ---------- K1: features [B][C][N] -> ft [B][N][C] ----------
__global__ __launch_bounds__(256) void transpose_kernel(
    const float* __restrict__ feat, float* __restrict__ ft)
{
    __shared__ float tile[64][65];                 // +1 pad
    const int b   = blockIdx.x & 7;                // XCD swizzle
    const int n0  = (blockIdx.x >> 3) << 6;
    const int tid = threadIdx.x;
    const float* __restrict__ fb = feat + (size_t)b * NCH * N_PTS;
    float* __restrict__ tb       = ft   + ((size_t)b * N_PTS + n0) * NCH;

#pragma unroll
    for (int j = 0; j < 16; ++j) {                 // read coalesced along n
        const int idx = j * 256 + tid;
        const int c = idx >> 6, nn = idx & 63;
        tile[c][nn] = __builtin_nontemporal_load(&fb[(size_t)c * N_PTS + n0 + nn]);
    }
    __syncthreads();
    const int c4 = tid & 15;
    const int r  = tid >> 4;
#pragma unroll
    for (int j = 0; j < 4; ++j) {                  // write 1KB dwordx4 per instr
        const int nn = j * 16 + r;
        f4 o;
        o.x = tile[c4 * 4 + 0][nn];
        o.y = tile[c4 * 4 + 1][nn];
        o.z = tile[c4 * 4 + 2][nn];
        o.w = tile[c4 * 4 + 3][nn];
        *(f4*)(&tb[(size_t)nn * NCH + c4 * 4]) = o;  // re-read by qg_main: keep cached
    }
}

// ---------- K2: fused ball query (block-shared staged scan) + gather ----------
// 4 waves/block, one query per wave. Phase-1: all 256 threads stage 256 pts/iter
// to double-buffered LDS; waves ballot from LDS. Phase-2: R6's gather (per-wave).
__global__ __launch_bounds__(256) void qg_main(
    const float* __restrict__ new_xyz,  // [B][M][3]
    const float* __restrict__ ft,       // [B][N][C]
    const float* __restrict__ xs, const float* __restrict__ ys,
    const float* __restrict__ zs,
    float* __restrict__ out)            // [B][67][M][NS]
{
    const int tid  = threadIdx.x;
    const int w    = tid >> 6;
    const int lane = tid & 63;
    const int b    = blockIdx.x & 7;               // XCD swizzle
    const int m    = ((blockIdx.x >> 3) << 2) + w;
    const int q    = (b << 10) + m;

    __shared__ float xbuf[2][CHUNK], ybuf[2][CHUNK], zbuf[2][CHUNK];
    __shared__ float pxyz[4][NSAMP][4];            // [wave][slot]{dx,dy,dz,bits(idx)}
    __shared__ float tile[4][32][33];
    __shared__ int   donef[4];

    const float cx = new_xyz[q * 3 + 0];
    const float cy = new_xyz[q * 3 + 1];
    const float cz = new_xyz[q * 3 + 2];
    const float* __restrict__ xsb = xs + (size_t)b * N_PTS;
    const float* __restrict__ ysb = ys + (size_t)b * N_PTS;
    const float* __restrict__ zsb = zs + (size_t)b * N_PTS;

    // ---- Phase 1: staged scan, 256 pts/iter, double-buffered ----
    const unsigned long long lt = (1ull << lane) - 1ull;
    int  cnt    = 0;
    bool mydone = false;

    // stage chunk 0
    xbuf[0][tid] = xsb[tid];
    ybuf[0][tid] = ysb[tid];
    zbuf[0][tid] = zsb[tid];
    if (tid < 4) donef[tid] = 0;
    __syncthreads();

    for (int i = 0; ; ++i) {
        const int base      = i * CHUNK;
        const int base_next = base + CHUNK;
        const bool more     = base_next < N_PTS;
        // prefetch next chunk into regs (overlaps LDS processing below)
        float nx = 0.f, ny = 0.f, nz = 0.f;
        if (more) {
            nx = xsb[base_next + tid];
            ny = ysb[base_next + tid];
            nz = zsb[base_next + tid];
        }

        if (!mydone) {
            const int cur = i & 1;
#pragma unroll
            for (int s = 0; s < 4; ++s) {          // 4 sub-chunks of 64, index order
                const int  o  = s * 64 + lane;
                const float px = xbuf[cur][o];
                const float py = ybuf[cur][o];
                const float pz = zbuf[cur][o];
                const float dx = __fsub_rn(cx, px);
                const float dy = __fsub_rn(cy, py);
                const float dz = __fsub_rn(cz, pz);
                const float d2 = __fadd_rn(__fadd_rn(__fmul_rn(dx, dx), __fmul_rn(dy, dy)),
                                           __fmul_rn(dz, dz));
                const bool hit = d2 < R2;
                const unsigned long long mk = __ballot(hit);
                if (hit) {
                    const int slot = cnt + __popcll(mk & lt);
                    if (slot < NSAMP) {
                        pxyz[w][slot][0] = -dx;    // = x - cx (exact negation)
                        pxyz[w][slot][1] = -dy;
                        pxyz[w][slot][2] = -dz;
                        pxyz[w][slot][3] = __int_as_float(base + o);
                    }
                }
                cnt += (int)__popcll(mk);
            }
            mydone = (cnt >= NSAMP);
            if (lane == 0) donef[w] = mydone ? 1 : 0;
        }

        // write next buffer (not read this iter), then one barrier
        if (more) {
            const int nxt = (i + 1) & 1;
            xbuf[nxt][tid] = nx;
            ybuf[nxt][tid] = ny;
            zbuf[nxt][tid] = nz;
        }
        __syncthreads();
        if (!more || (donef[0] & donef[1] & donef[2] & donef[3])) break;
    }

    // fill empty slots with slot 0 (reference broadcasts sorted_idx[...,0])
    if (lane < NSAMP && cnt < NSAMP) {
        float v0x, v0y, v0z, v0w;
        if (cnt > 0) {
            v0x = pxyz[w][0][0]; v0y = pxyz[w][0][1];
            v0z = pxyz[w][0][2]; v0w = pxyz[w][0][3];
        } else {
            v0x = __fsub_rn(xsb[0], cx); v0y = __fsub_rn(ysb[0], cy);
            v0z = __fsub_rn(zsb[0], cz); v0w = __int_as_float(0);
        }
        if (lane >= cnt) {
            pxyz[w][lane][0] = v0x; pxyz[w][lane][1] = v0y;
            pxyz[w][lane][2] = v0z; pxyz[w][lane][3] = v0w;
        }
    }
    // wave-synchronous from here: pxyz[w] consumed only by wave w

    float* __restrict__ ob = out + ((size_t)b * OUT_CH * M_Q + (size_t)m) * NSAMP;

    // ---- Phase 2a: centered xyz channels (24 lanes, 1 dwordx4 nt each) ----
    if (lane < 24) {
        const int c  = lane >> 3;        // 0..2
        const int s4 = lane & 7;
        f4 o;
        o.x = pxyz[w][s4 * 4 + 0][c];
        o.y = pxyz[w][s4 * 4 + 1][c];
        o.z = pxyz[w][s4 * 4 + 2][c];
        o.w = pxyz[w][s4 * 4 + 3][c];
        __builtin_nontemporal_store(o, (f4*)&ob[(size_t)c * (M_Q * NSAMP) + s4 * 4]);
    }

    // ---- Phase 2b: feature rows (256B contiguous), LDS transpose, nt stores ----
    const float* __restrict__ ftb = ft + (size_t)b * N_PTS * NCH;
    const int sgrp = lane >> 3;          // 0..7
    const int c4   = lane & 7;

#pragma unroll
    for (int chunk = 0; chunk < 2; ++chunk) {
        f4 vals[4];
#pragma unroll
        for (int i = 0; i < 4; ++i) {    // 8 lanes x 128B per row-half
            const int s = i * 8 + sgrp;
            const int n = __float_as_int(pxyz[w][s][3]);
            vals[i] = *(const f4*)(ftb + (size_t)n * NCH + chunk * 32 + c4 * 4);
        }
#pragma unroll
        for (int i = 0; i < 4; ++i) {    // [s][c] -> [c][s]
            const int s = i * 8 + sgrp;
            tile[w][c4 * 4 + 0][s] = vals[i].x;
            tile[w][c4 * 4 + 1][s] = vals[i].y;
            tile[w][c4 * 4 + 2][s] = vals[i].z;
            tile[w][c4 * 4 + 3][s] = vals[i].w;
        }
#pragma unroll
        for (int j = 0; j < 4; ++j) {    // 1KB nt store per instr
            const int c_loc = j * 8 + (lane >> 3);
            const int s4    = lane & 7;
            f4 o;
            o.x = tile[w][c_loc][s4 * 4 + 0];
            o.y = tile[w][c_loc][s4 * 4 + 1];
            o.z = tile[w][c_loc][s4 * 4 + 2];
            o.w = tile[w][c_loc][s4 * 4 + 3];
            __builtin_nontemporal_store(
                o, (f4*)&ob[(size_t)(3 + chunk * 32 + c_loc) * (M_Q * NSAMP) + s4 * 4]);
        }
    }
}

// ---------- fallback (ws too small): direct-gather kernel ----------
__global__ __launch_bounds__(256) void qg_fallback(
    const float* __restrict__ xyz, const float* __restrict__ new_xyz,
    const float* __restrict__ feat, float* __restrict__ out)
{
    const int tid  = threadIdx.x;
    const int w    = tid >> 6;
    const int lane = tid & 63;
    const int q    = blockIdx.x * 4 + w;
    const int b    = q >> 10;
    const int m    = q & (M_Q - 1);

    __shared__ int idx_sh[4][NSAMP];

    const float cx = new_xyz[q * 3 + 0];
    const float cy = new_xyz[q * 3 + 1];
    const float cz = new_xyz[q * 3 + 2];
    const float* __restrict__ xb = xyz + (size_t)b * N_PTS * 3;

    int cnt = 0;
    for (int base = 0; base < N_PTS && cnt < NSAMP; base += 64) {
        const int n = base + lane;
        const float dx = __fsub_rn(cx, xb[n * 3 + 0]);
        const float dy = __fsub_rn(cy, xb[n * 3 + 1]);
        const float dz = __fsub_rn(cz, xb[n * 3 + 2]);
        const float d2 = __fadd_rn(__fadd_rn(__fmul_rn(dx, dx), __fmul_rn(dy, dy)),
                                   __fmul_rn(dz, dz));
        const bool hit = d2 < R2;
        const unsigned long long mk = __ballot(hit);
        if (hit) {
            const int slot = cnt + __popcll(mk & ((1ull << lane) - 1ull));
            if (slot < NSAMP) idx_sh[w][slot] = n;
        }
        cnt += (int)__popcll(mk);
    }
    __syncthreads();
    if (lane < NSAMP) {
        const int v0 = (cnt > 0) ? idx_sh[w][0] : 0;
        if (lane >= cnt) idx_sh[w][lane] = v0;
    }
    __syncthreads();

    const float* __restrict__ fb = feat + (size_t)b * NCH * N_PTS;
    float* __restrict__ ob = out + ((size_t)b * OUT_CH * M_Q + (size_t)m) * NSAMP;
    for (int e = lane; e < OUT_CH * NSAMP; e += 64) {
        const int c = e >> 5, s = e & 31;
        const int n = idx_sh[w][s];
        float v;
        if (c < 3) {
            const float ctr = (c == 0) ? cx : ((c == 1) ? cy : cz);
            v = __fsub_rn(xb[n * 3 + c], ctr);
        } else {
            v = fb[(size_t)(c - 3) * N_PTS + n];
        }
        ob[(size_t)c * (M_Q * NSAMP) + s] = v;
    }
}

extern "C" void kernel_launch(void* const* d_in, const int* in_sizes, int n_in,
                              void* d_out, int out_size, void* d_ws, size_t ws_size,
                              hipStream_t stream) {
    const float* xyz     = (const float*)d_in[0];
    const float* new_xyz = (const float*)d_in[1];
    const float* feat    = (const float*)d_in[2];
    float* out           = (float*)d_out;

    const size_t ft_elems  = (size_t)B_SZ * N_PTS * NCH;        // 8388608
    const size_t soa_elems = (size_t)B_SZ * N_PTS;              // 131072
    const size_t need = (ft_elems + 3 * soa_elems) * sizeof(float);  // ~35.1 MB

    float* ft = (float*)d_ws;
    float* xs = ft + ft_elems;
    float* ys = xs + soa_elems;
    float* zs = ys + soa_elems;

    if (ws_size >= need) {
        soa_kernel<<<(B_SZ * N_PTS) / 256, 256, 0, stream>>>(xyz, xs, ys, zs);
        transpose_kernel<<<B_SZ * (N_PTS / 64), 256, 0, stream>>>(feat, ft);
        qg_main<<<(B_SZ * M_Q) / 4, 256, 0, stream>>>(new_xyz, ft, xs, ys, zs, out);
    } else {
        qg_fallback<<<(B_SZ * M_Q) / 4, 256, 0, stream>>>(xyz, new_xyz, feat, out);
    }
}

// Round 11
// 125.642 us; speedup vs baseline: 1.0431x; 1.0313x over previous
//
#include <hip/hip_runtime.h>

// QueryAndGroup: ball_query(r=0.2, ns=32) + group xyz (centered) + group features.
//   xyz      [8][16384][3] f32   d_in[0]
//   new_xyz  [8][1024][3]  f32   d_in[1]
//   features [8][64][16384] f32  d_in[2]
//   out      [8][67][1024][32] f32
//
// FINAL (R11 = exact R6 revert, best measured 125.6us):
//   K1 transpose: feat [B][C][N] -> ft [B][N][C] in d_ws (+ xyz AoS->SoA).
//   K2 qg_main<SOA>: wave-per-query ordered ballot scan over SoA coords
//   (24 line-requests / 128 pts — measured-minimal), no __syncthreads
//   (per-wave LDS), prefetch-pipelined scan, full-line feature gathers,
//   1KB nontemporal dwordx4 output stores, XCD swizzle b=blockIdx&7.
// Post-R6 attempts (fat overlap / packed f4 / split scan / LDS staging) all
// measured neutral-to-negative; dur is dominated by harness fill (~45us of
// 281MB ws re-poison) + launch slack + transaction-minimal phase-2 floor.

#define N_PTS   16384
#define M_Q     1024
#define B_SZ    8
#define NSAMP   32
#define NCH     64
#define R2      0.04f
#define OUT_CH  (3 + NCH)

typedef float f4 __attribute__((ext_vector_type(4)));

// ---------- features [B][C][N] -> ft [B][N][C]; also xyz AoS -> SoA ----------
__global__ __launch_bounds__(256) void transpose_kernel(
    const float* __restrict__ feat, const float* __restrict__ xyz,
    float* __restrict__ ft,
    float* __restrict__ xs, float* __restrict__ ys, float* __restrict__ zs)
{
    __shared__ float tile[64][65];                 // +1 pad
    const int b   = blockIdx.x & 7;                // XCD swizzle: batch = blockIdx % 8
    const int n0  = (blockIdx.x >> 3) << 6;
    const int tid = threadIdx.x;
    const float* __restrict__ fb = feat + (size_t)b * NCH * N_PTS;
    float* __restrict__ tb       = ft   + ((size_t)b * N_PTS + n0) * NCH;

    // SoA coords for this 64-point tile (threads 0..63)
    if (xs && tid < 64) {
        const int p = n0 + tid;
        const float* src = xyz + ((size_t)b * N_PTS + p) * 3;
        xs[(size_t)b * N_PTS + p] = src[0];
        ys[(size_t)b * N_PTS + p] = src[1];
        zs[(size_t)b * N_PTS + p] = src[2];
    }

#pragma unroll
    for (int j = 0; j < 16; ++j) {                 // read coalesced along n (single-use -> nt)
        const int idx = j * 256 + tid;
        const int c = idx >> 6, nn = idx & 63;
        tile[c][nn] = __builtin_nontemporal_load(&fb[(size_t)c * N_PTS + n0 + nn]);
    }
    __syncthreads();
    const int c4 = tid & 15;
    const int r  = tid >> 4;
#pragma unroll
    for (int j = 0; j < 4; ++j) {                  // write: 1KB dwordx4 per instr
        const int nn = j * 16 + r;
        f4 o;
        o.x = tile[c4 * 4 + 0][nn];
        o.y = tile[c4 * 4 + 1][nn];
        o.z = tile[c4 * 4 + 2][nn];
        o.w = tile[c4 * 4 + 3][nn];
        *(f4*)(&tb[(size_t)nn * NCH + c4 * 4]) = o;  // re-read later: keep cached
    }
}

// ---------- main: ball query + grouped gather. SOA: coords from xs/ys/zs ----------
// 4 waves/block, one query per wave, NO __syncthreads (all LDS per-wave).
template <bool SOA>
__global__ __launch_bounds__(256) void qg_main(
    const float* __restrict__ xyz,      // [B][N][3]
    const float* __restrict__ new_xyz,  // [B][M][3]
    const float* __restrict__ ft,       // [B][N][C]
    const float* __restrict__ xs, const float* __restrict__ ys,
    const float* __restrict__ zs,
    float* __restrict__ out)            // [B][67][M][NS]
{
    const int tid  = threadIdx.x;
    const int w    = tid >> 6;
    const int lane = tid & 63;
    const int b    = blockIdx.x & 7;               // XCD swizzle
    const int m    = ((blockIdx.x >> 3) << 2) + w;
    const int q    = (b << 10) + m;

    __shared__ float pxyz[4][NSAMP][4];            // [wave][slot] = {x, y, z, bits(idx)}
    __shared__ float tile[4][32][33];              // [wave][c_local][s]

    const float cx = new_xyz[q * 3 + 0];
    const float cy = new_xyz[q * 3 + 1];
    const float cz = new_xyz[q * 3 + 2];
    const float* __restrict__ xb  = xyz + (size_t)b * N_PTS * 3;
    const float* __restrict__ xsb = SOA ? xs + (size_t)b * N_PTS : nullptr;
    const float* __restrict__ ysb = SOA ? ys + (size_t)b * N_PTS : nullptr;
    const float* __restrict__ zsb = SOA ? zs + (size_t)b * N_PTS : nullptr;

    // ---- Phase 1: ordered ball query, software-pipelined 2x64 chunks ----
    const unsigned long long lmask = (1ull << lane) - 1ull;
    int cnt = 0;
    float Ax, Ay, Az, Bx, By, Bz;
    if (SOA) {
        Ax = xsb[lane];      Ay = ysb[lane];      Az = zsb[lane];
        Bx = xsb[64 + lane]; By = ysb[64 + lane]; Bz = zsb[64 + lane];
    } else {
        Ax = xb[lane * 3 + 0];        Ay = xb[lane * 3 + 1];        Az = xb[lane * 3 + 2];
        Bx = xb[(64 + lane) * 3 + 0]; By = xb[(64 + lane) * 3 + 1]; Bz = xb[(64 + lane) * 3 + 2];
    }

    for (int base = 0; ; base += 128) {
        // prefetch next 128 points before touching this iteration's ballots
        const int  nbase = base + 128;
        const bool more  = nbase < N_PTS;
        const int  pA = more ? nbase + lane : lane;   // dummy reload if done (L1 hit)
        const int  pB = pA + 64;
        float nAx, nAy, nAz, nBx, nBy, nBz;
        if (SOA) {
            nAx = xsb[pA]; nAy = ysb[pA]; nAz = zsb[pA];
            nBx = xsb[pB]; nBy = ysb[pB]; nBz = zsb[pB];
        } else {
            nAx = xb[pA * 3 + 0]; nAy = xb[pA * 3 + 1]; nAz = xb[pA * 3 + 2];
            nBx = xb[pB * 3 + 0]; nBy = xb[pB * 3 + 1]; nBz = xb[pB * 3 + 2];
        }

        {   // chunk A (index order before B)
            const float dx = __fsub_rn(cx, Ax), dy = __fsub_rn(cy, Ay), dz = __fsub_rn(cz, Az);
            const float d2 = __fadd_rn(__fadd_rn(__fmul_rn(dx, dx), __fmul_rn(dy, dy)),
                                       __fmul_rn(dz, dz));
            const bool hit = d2 < R2;
            const unsigned long long mk = __ballot(hit);
            if (hit) {
                const int slot = cnt + __popcll(mk & lmask);
                if (slot < NSAMP) {
                    pxyz[w][slot][0] = Ax;
                    pxyz[w][slot][1] = Ay;
                    pxyz[w][slot][2] = Az;
                    pxyz[w][slot][3] = __int_as_float(base + lane);
                }
            }
            cnt += (int)__popcll(mk);
        }
        {   // chunk B
            const float dx = __fsub_rn(cx, Bx), dy = __fsub_rn(cy, By), dz = __fsub_rn(cz, Bz);
            const float d2 = __fadd_rn(__fadd_rn(__fmul_rn(dx, dx), __fmul_rn(dy, dy)),
                                       __fmul_rn(dz, dz));
            const bool hit = d2 < R2;
            const unsigned long long mk = __ballot(hit);
            if (hit) {
                const int slot = cnt + __popcll(mk & lmask);
                if (slot < NSAMP) {
                    pxyz[w][slot][0] = Bx;
                    pxyz[w][slot][1] = By;
                    pxyz[w][slot][2] = Bz;
                    pxyz[w][slot][3] = __int_as_float(base + 64 + lane);
                }
            }
            cnt += (int)__popcll(mk);
        }
        if (cnt >= NSAMP || !more) break;
        Ax = nAx; Ay = nAy; Az = nAz;
        Bx = nBx; By = nBy; Bz = nBz;
    }

    // fill empty slots with slot 0 (reference broadcasts sorted_idx[...,0])
    if (lane < NSAMP && cnt < NSAMP) {
        float v0x, v0y, v0z, v0w;
        if (cnt > 0) {
            v0x = pxyz[w][0][0]; v0y = pxyz[w][0][1];
            v0z = pxyz[w][0][2]; v0w = pxyz[w][0][3];
        } else {
            v0x = xb[0]; v0y = xb[1]; v0z = xb[2]; v0w = __int_as_float(0);
        }
        if (lane >= cnt) {
            pxyz[w][lane][0] = v0x; pxyz[w][lane][1] = v0y;
            pxyz[w][lane][2] = v0z; pxyz[w][lane][3] = v0w;
        }
    }
    // wave-synchronous: same-wave ds_write -> ds_read ordered by lgkmcnt

    float* __restrict__ ob = out + ((size_t)b * OUT_CH * M_Q + (size_t)m) * NSAMP;

    // ---- Phase 2a: centered xyz channels straight from LDS (24 lanes, 1 dwordx4) ----
    if (lane < 24) {
        const int c  = lane >> 3;        // 0..2
        const int s4 = lane & 7;
        const float ctr = (c == 0) ? cx : ((c == 1) ? cy : cz);
        f4 o;
        o.x = __fsub_rn(pxyz[w][s4 * 4 + 0][c], ctr);
        o.y = __fsub_rn(pxyz[w][s4 * 4 + 1][c], ctr);
        o.z = __fsub_rn(pxyz[w][s4 * 4 + 2][c], ctr);
        o.w = __fsub_rn(pxyz[w][s4 * 4 + 3][c], ctr);
        __builtin_nontemporal_store(o, (f4*)&ob[(size_t)c * (M_Q * NSAMP) + s4 * 4]);
    }

    // ---- Phase 2b: feature rows (256B contiguous), LDS transpose, dwordx4 nt stores ----
    const float* __restrict__ ftb = ft + (size_t)b * N_PTS * NCH;
    const int sgrp = lane >> 3;          // 0..7
    const int c4   = lane & 7;           // float4 within 32-ch chunk

#pragma unroll
    for (int chunk = 0; chunk < 2; ++chunk) {
        f4 vals[4];
#pragma unroll
        for (int i = 0; i < 4; ++i) {    // 8 lanes x 128B per row-half
            const int s = i * 8 + sgrp;
            const int n = __float_as_int(pxyz[w][s][3]);
            vals[i] = *(const f4*)(ftb + (size_t)n * NCH + chunk * 32 + c4 * 4);
        }
#pragma unroll
        for (int i = 0; i < 4; ++i) {    // [s][c] -> [c][s]  (<=2-way banks: free)
            const int s = i * 8 + sgrp;
            tile[w][c4 * 4 + 0][s] = vals[i].x;
            tile[w][c4 * 4 + 1][s] = vals[i].y;
            tile[w][c4 * 4 + 2][s] = vals[i].z;
            tile[w][c4 * 4 + 3][s] = vals[i].w;
        }
#pragma unroll
        for (int j = 0; j < 4; ++j) {    // 1KB nt store per instr
            const int c_loc = j * 8 + (lane >> 3);
            const int s4    = lane & 7;
            f4 o;
            o.x = tile[w][c_loc][s4 * 4 + 0];
            o.y = tile[w][c_loc][s4 * 4 + 1];
            o.z = tile[w][c_loc][s4 * 4 + 2];
            o.w = tile[w][c_loc][s4 * 4 + 3];
            __builtin_nontemporal_store(
                o, (f4*)&ob[(size_t)(3 + chunk * 32 + c_loc) * (M_Q * NSAMP) + s4 * 4]);
        }
    }
}

// ---------- fallback (ws too small): direct-gather kernel ----------
__global__ __launch_bounds__(256) void qg_fallback(
    const float* __restrict__ xyz, const float* __restrict__ new_xyz,
    const float* __restrict__ feat, float* __restrict__ out)
{
    const int tid  = threadIdx.x;
    const int w    = tid >> 6;
    const int lane = tid & 63;
    const int q    = blockIdx.x * 4 + w;
    const int b    = q >> 10;
    const int m    = q & (M_Q - 1);

    __shared__ int idx_sh[4][NSAMP];

    const float cx = new_xyz[q * 3 + 0];
    const float cy = new_xyz[q * 3 + 1];
    const float cz = new_xyz[q * 3 + 2];
    const float* __restrict__ xb = xyz + (size_t)b * N_PTS * 3;

    int cnt = 0;
    for (int base = 0; base < N_PTS && cnt < NSAMP; base += 64) {
        const int n = base + lane;
        const float dx = __fsub_rn(cx, xb[n * 3 + 0]);
        const float dy = __fsub_rn(cy, xb[n * 3 + 1]);
        const float dz = __fsub_rn(cz, xb[n * 3 + 2]);
        const float d2 = __fadd_rn(__fadd_rn(__fmul_rn(dx, dx), __fmul_rn(dy, dy)),
                                   __fmul_rn(dz, dz));
        const bool hit = d2 < R2;
        const unsigned long long mk = __ballot(hit);
        if (hit) {
            const int slot = cnt + __popcll(mk & ((1ull << lane) - 1ull));
            if (slot < NSAMP) idx_sh[w][slot] = n;
        }
        cnt += (int)__popcll(mk);
    }
    __syncthreads();
    if (lane < NSAMP) {
        const int v0 = (cnt > 0) ? idx_sh[w][0] : 0;
        if (lane >= cnt) idx_sh[w][lane] = v0;
    }
    __syncthreads();

    const float* __restrict__ fb = feat + (size_t)b * NCH * N_PTS;
    float* __restrict__ ob = out + ((size_t)b * OUT_CH * M_Q + (size_t)m) * NSAMP;
    for (int e = lane; e < OUT_CH * NSAMP; e += 64) {
        const int c = e >> 5, s = e & 31;
        const int n = idx_sh[w][s];
        float v;
        if (c < 3) {
            const float ctr = (c == 0) ? cx : ((c == 1) ? cy : cz);
            v = __fsub_rn(xb[n * 3 + c], ctr);
        } else {
            v = fb[(size_t)(c - 3) * N_PTS + n];
        }
        ob[(size_t)c * (M_Q * NSAMP) + s] = v;
    }
}

extern "C" void kernel_launch(void* const* d_in, const int* in_sizes, int n_in,
                              void* d_out, int out_size, void* d_ws, size_t ws_size,
                              hipStream_t stream) {
    const float* xyz     = (const float*)d_in[0];
    const float* new_xyz = (const float*)d_in[1];
    const float* feat    = (const float*)d_in[2];
    float* out           = (float*)d_out;

    const size_t ft_elems  = (size_t)B_SZ * N_PTS * NCH;        // 8388608
    const size_t soa_elems = (size_t)B_SZ * N_PTS;              // 131072
    const size_t need_soa  = (ft_elems + 3 * soa_elems) * sizeof(float);  // ~35.1 MB
    const size_t need_ft   = ft_elems * sizeof(float);                    // 33.6 MB

    float* ft = (float*)d_ws;
    float* xs = ft + ft_elems;
    float* ys = xs + soa_elems;
    float* zs = ys + soa_elems;

    if (ws_size >= need_soa) {
        transpose_kernel<<<B_SZ * (N_PTS / 64), 256, 0, stream>>>(feat, xyz, ft, xs, ys, zs);
        qg_main<true><<<(B_SZ * M_Q) / 4, 256, 0, stream>>>(
            xyz, new_xyz, ft, xs, ys, zs, out);
    } else if (ws_size >= need_ft) {
        transpose_kernel<<<B_SZ * (N_PTS / 64), 256, 0, stream>>>(
            feat, xyz, ft, nullptr, nullptr, nullptr);
        qg_main<false><<<(B_SZ * M_Q) / 4, 256, 0, stream>>>(
            xyz, new_xyz, ft, nullptr, nullptr, nullptr, out);
    } else {
        qg_fallback<<<(B_SZ * M_Q) / 4, 256, 0, stream>>>(xyz, new_xyz, feat, out);
    }
}